// Round 1
// baseline (3762.761 us; speedup 1.0000x reference)
//
#include <hip/hip_runtime.h>
#include <hip/hip_bf16.h>

namespace {

constexpr int Hn = 50;    // hidden size
constexpr int Bn = 2048;  // batch
constexpr int Tn = 512;   // sequence length

__device__ __forceinline__ float rlane(float v, int k) {
  return __builtin_bit_cast(float, __builtin_amdgcn_readlane(__builtin_bit_cast(int, v), k));
}

__device__ __forceinline__ float fsig(float x) {
  // x very negative -> expf(-x)=inf -> 1/(1+inf)=0 : safe, no NaN
  return 1.0f / (1.0f + __expf(-x));
}

__device__ __forceinline__ float ftanh(float x) {
  float a = fabsf(x);
  float e = __expf(-2.0f * a);          // in (0,1], no overflow
  float t = (1.0f - e) / (1.0f + e);
  return copysignf(t, x);
}

template <typename ST> __device__ __forceinline__ float ld1(const ST* p);
template <> __device__ __forceinline__ float ld1<float>(const float* p) { return *p; }
template <> __device__ __forceinline__ float ld1<__hip_bfloat16>(const __hip_bfloat16* p) {
  return __bfloat162float(*p);
}
template <typename ST> __device__ __forceinline__ void st1(ST* p, float v);
template <> __device__ __forceinline__ void st1<float>(float* p, float v) { *p = v; }
template <> __device__ __forceinline__ void st1<__hip_bfloat16>(__hip_bfloat16* p, float v) {
  *p = __float2bfloat16(v);
}

// ---------------- Layer 1: input is scalar x[b][t] ----------------
// One wave handles 2 batch elements. Lane q (<50) owns gate-quad
// {i_q, f_q, g_q, o_q}; weights register-resident; cell update in-thread.
template <typename ST>
__global__ __launch_bounds__(256, 1) void lstm_l1(
    const float* __restrict__ x,     // [B][T]
    const float* __restrict__ wih,   // [4H][1]
    const float* __restrict__ whh,   // [4H][H]
    const float* __restrict__ bias,  // [4H]
    ST* __restrict__ hseq)           // [T][B][H]
{
  const int lane = threadIdx.x & 63;
  const int wv   = threadIdx.x >> 6;
  const int e0   = (blockIdx.x * 4 + wv) * 2;
  const int e1   = e0 + 1;
  const bool act = lane < Hn;
  const int q    = act ? lane : 0;   // clamp so all global reads are in-bounds

  float wi[4], bb[4], wh[4][Hn];
#pragma unroll
  for (int j = 0; j < 4; ++j) {
    const int row = j * Hn + q;
    wi[j] = wih[row];
    bb[j] = bias[row];
#pragma unroll
    for (int k = 0; k < Hn; ++k) wh[j][k] = whh[row * Hn + k];
  }
  if (!act) {
#pragma unroll
    for (int j = 0; j < 4; ++j) { wi[j] = 0.f; bb[j] = 0.f; }
  }

  float h0 = 0.f, h1 = 0.f, c0 = 0.f, c1 = 0.f;
  const float* xp0 = x + (size_t)e0 * Tn;
  const float* xp1 = x + (size_t)e1 * Tn;

#pragma unroll 1
  for (int tb = 0; tb < Tn; tb += 64) {
    const float xv0 = xp0[tb + lane];  // 64 timesteps staged across lanes
    const float xv1 = xp1[tb + lane];
#pragma unroll 1
    for (int ti = 0; ti < 64; ++ti) {
      const float xk0 = rlane(xv0, ti);
      const float xk1 = rlane(xv1, ti);
      float a0[4], a1[4];
#pragma unroll
      for (int j = 0; j < 4; ++j) {
        a0[j] = fmaf(wi[j], xk0, bb[j]);
        a1[j] = fmaf(wi[j], xk1, bb[j]);
      }
#pragma unroll
      for (int k = 0; k < Hn; ++k) {
        const float hk0 = rlane(h0, k);
        const float hk1 = rlane(h1, k);
#pragma unroll
        for (int j = 0; j < 4; ++j) {
          a0[j] = fmaf(wh[j][k], hk0, a0[j]);
          a1[j] = fmaf(wh[j][k], hk1, a1[j]);
        }
      }
      {
        const float i0 = fsig(a0[0]), f0 = fsig(a0[1]);
        const float g0 = ftanh(a0[2]), o0 = fsig(a0[3]);
        c0 = fmaf(f0, c0, i0 * g0);
        h0 = o0 * ftanh(c0);
        const float i1 = fsig(a1[0]), f1 = fsig(a1[1]);
        const float g1 = ftanh(a1[2]), o1 = fsig(a1[3]);
        c1 = fmaf(f1, c1, i1 * g1);
        h1 = o1 * ftanh(c1);
      }
      if (act) {
        const int t = tb + ti;
        st1(hseq + ((size_t)t * Bn + e0) * Hn + lane, h0);
        st1(hseq + ((size_t)t * Bn + e1) * Hn + lane, h1);
      }
    }
  }
}

// ---------------- Layers 2/3: input is h-sequence [T][B][H] ----------------
template <typename ST, bool WRITE_H, bool DO_FC>
__global__ __launch_bounds__(256, 1) void lstm_l23(
    const ST* __restrict__ xseq,     // [T][B][H] (may alias hseq: in-place)
    const float* __restrict__ wih,   // [4H][H]
    const float* __restrict__ whh,   // [4H][H]
    const float* __restrict__ bias,  // [4H]
    ST* __restrict__ hseq,           // [T][B][H]
    const float* __restrict__ wfc,   // [H]
    const float* __restrict__ bfc,   // [1]
    float* __restrict__ out)         // [B]
{
  const int lane = threadIdx.x & 63;
  const int wv   = threadIdx.x >> 6;
  const int e0   = (blockIdx.x * 4 + wv) * 2;
  const int e1   = e0 + 1;
  const bool act = lane < Hn;
  const int q    = act ? lane : 0;

  float wi[4][Hn], wh[4][Hn], bb[4];
#pragma unroll
  for (int j = 0; j < 4; ++j) {
    const int row = j * Hn + q;
    bb[j] = act ? bias[row] : 0.f;
#pragma unroll
    for (int k = 0; k < Hn; ++k) {
      wi[j][k] = wih[row * Hn + k];
      wh[j][k] = whh[row * Hn + k];
    }
  }

  float h0 = 0.f, h1 = 0.f, c0 = 0.f, c1 = 0.f;

  const ST* xp0 = xseq + (size_t)e0 * Hn + lane;
  const ST* xp1 = xseq + (size_t)e1 * Hn + lane;
  constexpr size_t tstride = (size_t)Bn * Hn;

  float xv0 = act ? ld1(xp0) : 0.f;
  float xv1 = act ? ld1(xp1) : 0.f;

#pragma unroll 1
  for (int t = 0; t < Tn; ++t) {
    // prefetch next timestep's input (reads slot t+1; we only write slot t)
    const size_t tnoff = (size_t)(t + 1 < Tn ? t + 1 : t) * tstride;
    const float nx0 = act ? ld1(xp0 + tnoff) : 0.f;
    const float nx1 = act ? ld1(xp1 + tnoff) : 0.f;

    float a0[4], a1[4];
#pragma unroll
    for (int j = 0; j < 4; ++j) { a0[j] = bb[j]; a1[j] = bb[j]; }
#pragma unroll
    for (int k = 0; k < Hn; ++k) {
      const float xk0 = rlane(xv0, k);
      const float xk1 = rlane(xv1, k);
      const float hk0 = rlane(h0, k);
      const float hk1 = rlane(h1, k);
#pragma unroll
      for (int j = 0; j < 4; ++j) {
        a0[j] = fmaf(wi[j][k], xk0, a0[j]);
        a1[j] = fmaf(wi[j][k], xk1, a1[j]);
        a0[j] = fmaf(wh[j][k], hk0, a0[j]);
        a1[j] = fmaf(wh[j][k], hk1, a1[j]);
      }
    }
    {
      const float i0 = fsig(a0[0]), f0 = fsig(a0[1]);
      const float g0 = ftanh(a0[2]), o0 = fsig(a0[3]);
      c0 = fmaf(f0, c0, i0 * g0);
      h0 = o0 * ftanh(c0);
      const float i1 = fsig(a1[0]), f1 = fsig(a1[1]);
      const float g1 = ftanh(a1[2]), o1 = fsig(a1[3]);
      c1 = fmaf(f1, c1, i1 * g1);
      h1 = o1 * ftanh(c1);
    }
    if (WRITE_H && act) {
      st1(hseq + (size_t)t * tstride + (size_t)e0 * Hn + lane, h0);
      st1(hseq + (size_t)t * tstride + (size_t)e1 * Hn + lane, h1);
    }
    xv0 = nx0;
    xv1 = nx1;
  }

  if (DO_FC) {
    const float wf = act ? wfc[q] : 0.f;
    float p0 = act ? h0 * wf : 0.f;
    float p1 = act ? h1 * wf : 0.f;
#pragma unroll
    for (int off = 32; off > 0; off >>= 1) {
      p0 += __shfl_xor(p0, off);
      p1 += __shfl_xor(p1, off);
    }
    if (lane == 0) {
      const float bv = bfc[0];
      out[e0] = p0 + bv;
      out[e1] = p1 + bv;
    }
  }
}

}  // namespace

extern "C" void kernel_launch(void* const* d_in, const int* in_sizes, int n_in,
                              void* d_out, int out_size, void* d_ws, size_t ws_size,
                              hipStream_t stream) {
  const float* x    = (const float*)d_in[0];
  const float* wih1 = (const float*)d_in[1];
  const float* whh1 = (const float*)d_in[2];
  const float* b1   = (const float*)d_in[3];
  const float* wih2 = (const float*)d_in[4];
  const float* whh2 = (const float*)d_in[5];
  const float* b2   = (const float*)d_in[6];
  const float* wih3 = (const float*)d_in[7];
  const float* whh3 = (const float*)d_in[8];
  const float* b3   = (const float*)d_in[9];
  const float* wfc  = (const float*)d_in[10];
  const float* bfc  = (const float*)d_in[11];
  float* out = (float*)d_out;

  dim3 grid(Bn / 8), blk(256);  // 4 waves/block, 2 elements/wave
  const size_t need32 = (size_t)Tn * Bn * Hn * sizeof(float);  // 200 MiB

  if (ws_size >= need32) {
    float* buf = (float*)d_ws;
    lstm_l1<float><<<grid, blk, 0, stream>>>(x, wih1, whh1, b1, buf);
    lstm_l23<float, true, false><<<grid, blk, 0, stream>>>(
        buf, wih2, whh2, b2, buf, nullptr, nullptr, nullptr);
    lstm_l23<float, false, true><<<grid, blk, 0, stream>>>(
        buf, wih3, whh3, b3, nullptr, wfc, bfc, out);
  } else {
    // fallback: bf16 h-sequence (100 MiB) if workspace is small
    __hip_bfloat16* buf = (__hip_bfloat16*)d_ws;
    lstm_l1<__hip_bfloat16><<<grid, blk, 0, stream>>>(x, wih1, whh1, b1, buf);
    lstm_l23<__hip_bfloat16, true, false><<<grid, blk, 0, stream>>>(
        buf, wih2, whh2, b2, buf, nullptr, nullptr, nullptr);
    lstm_l23<__hip_bfloat16, false, true><<<grid, blk, 0, stream>>>(
        buf, wih3, whh3, b3, nullptr, wfc, bfc, out);
  }
}

// Round 2
// 2550.312 us; speedup vs baseline: 1.4754x; 1.4754x over previous
//
#include <hip/hip_runtime.h>

namespace {

constexpr int Hn = 50;    // hidden size
constexpr int Bn = 2048;  // batch
constexpr int Tn = 512;   // sequence length
constexpr int Hp = 52;    // padded K extent (multiple of 4, zero-padded)

__device__ __forceinline__ float fsig(float x) {
  return 1.0f / (1.0f + __expf(-x));  // x<<0 -> exp=inf -> 0 : safe
}
__device__ __forceinline__ float ftanh(float x) {
  float a = fabsf(x);
  float e = __expf(-2.0f * a);        // in (0,1]
  float t = (1.0f - e) / (1.0f + e);
  return copysignf(t, x);
}
__device__ __forceinline__ float rlane(float v, int k) {
  return __builtin_bit_cast(float, __builtin_amdgcn_readlane(__builtin_bit_cast(int, v), k));
}

// ============================================================================
// 2-wave cooperative LSTM step. Block = 128 threads = 2 waves, 2 batch elems.
// wave0 holds weight rows of gates {i,f}; wave1 holds {g,o}. Lane q = cell q.
// h and x are broadcast via LDS (conflict-free same-address float4 reads);
// cross-gates exchanged through s_ex; each wave updates one element's cell.
// Max weight regs per lane: 4 x 52 = 208 -> fits under the 256 arch-VGPR cap.
// ============================================================================

// -------- Layers 2/3: input sequence [T][B][H] --------
template <bool WRITE_H, bool DO_FC>
__global__ __launch_bounds__(128, 2) void lstm_mid(
    const float* __restrict__ xseq,  // [T][B][H] (may alias hseq: in-place)
    const float* __restrict__ wih,   // [4H][H]
    const float* __restrict__ whh,   // [4H][H]
    const float* __restrict__ bias,  // [4H]
    float* __restrict__ hseq,        // [T][B][H]
    const float* __restrict__ wfc,   // [H]
    const float* __restrict__ bfc,   // [1]
    float* __restrict__ out)         // [B]
{
  __shared__ float s_x[2][Hp];       // current x_t, both elems (pad = 0)
  __shared__ float s_h[2][Hp];       // h_{t-1}, both elems (pad = 0)
  __shared__ float s_ex[2][Hn][2];   // cross-gate exchange [elem][cell][gateA/B]

  const int lane = threadIdx.x & 63;
  const int wv   = threadIdx.x >> 6;   // 0: gates i,f   1: gates g,o
  const int eb   = blockIdx.x * 2;
  const int me   = eb + wv;            // element this wave cell-updates
  const bool act = lane < Hn;
  const int q    = act ? lane : 0;
  const int gA   = 2 * wv, gB = gA + 1;

  float wiA[Hp], wiB[Hp], whA[Hp], whB[Hp];
#pragma unroll
  for (int k = 0; k < Hn; ++k) {
    wiA[k] = wih[(gA * Hn + q) * Hn + k];
    wiB[k] = wih[(gB * Hn + q) * Hn + k];
    whA[k] = whh[(gA * Hn + q) * Hn + k];
    whB[k] = whh[(gB * Hn + q) * Hn + k];
  }
  wiA[50] = wiA[51] = wiB[50] = wiB[51] = 0.f;
  whA[50] = whA[51] = whB[50] = whB[51] = 0.f;
  const float bA = act ? bias[gA * Hn + q] : 0.f;
  const float bB = act ? bias[gB * Hn + q] : 0.f;

  if (threadIdx.x < 2 * Hp) {
    const int e = threadIdx.x / Hp, c = threadIdx.x % Hp;
    s_h[e][c] = 0.f;
    s_x[e][c] = (c < Hn) ? xseq[((size_t)0 * Bn + eb + e) * Hn + c] : 0.f;
  }
  __syncthreads();

  float cst = 0.f, hreg = 0.f;

#pragma unroll 1
  for (int t = 0; t < Tn; ++t) {
    // prefetch next x for my element (read slot t+1; slot t written below)
    const int tn = (t + 1 < Tn) ? t + 1 : t;
    const float xnext = act ? xseq[((size_t)tn * Bn + me) * Hn + lane] : 0.f;

    float aA0 = bA, aB0 = bB, aA1 = bA, aB1 = bB;
#pragma unroll
    for (int kb = 0; kb < 13; ++kb) {
      const float4 vx0 = *(const float4*)&s_x[0][kb * 4];
      const float4 vx1 = *(const float4*)&s_x[1][kb * 4];
      const float4 vh0 = *(const float4*)&s_h[0][kb * 4];
      const float4 vh1 = *(const float4*)&s_h[1][kb * 4];
#define K8(dk, C)                                      \
  aA0 = fmaf(wiA[kb * 4 + dk], vx0.C, aA0);            \
  aB0 = fmaf(wiB[kb * 4 + dk], vx0.C, aB0);            \
  aA1 = fmaf(wiA[kb * 4 + dk], vx1.C, aA1);            \
  aB1 = fmaf(wiB[kb * 4 + dk], vx1.C, aB1);            \
  aA0 = fmaf(whA[kb * 4 + dk], vh0.C, aA0);            \
  aB0 = fmaf(whB[kb * 4 + dk], vh0.C, aB0);            \
  aA1 = fmaf(whA[kb * 4 + dk], vh1.C, aA1);            \
  aB1 = fmaf(whB[kb * 4 + dk], vh1.C, aB1);
      K8(0, x) K8(1, y) K8(2, z) K8(3, w)
#undef K8
    }

    // exchange: write my 2 gates for the OTHER element
    const float exA = wv ? aA0 : aA1;
    const float exB = wv ? aB0 : aB1;
    const float myA = wv ? aA1 : aA0;
    const float myB = wv ? aB1 : aB0;
    if (act) {
      s_ex[1 - wv][q][0] = exA;
      s_ex[1 - wv][q][1] = exB;
    }
    __syncthreads();
    const float oA = s_ex[wv][q][0];
    const float oB = s_ex[wv][q][1];
    // wave0: my = i,f  oth = g,o ; wave1: my = g,o  oth = i,f
    const float gi = wv ? oA : myA;
    const float gf = wv ? oB : myB;
    const float gg = wv ? myA : oA;
    const float go = wv ? myB : oB;
    const float I = fsig(gi), F = fsig(gf), G = ftanh(gg), O = fsig(go);
    cst  = fmaf(F, cst, I * G);
    hreg = O * ftanh(cst);

    if (act) {
      s_h[wv][lane] = hreg;
      s_x[wv][lane] = xnext;
      if (WRITE_H) hseq[((size_t)t * Bn + me) * Hn + lane] = hreg;
    }
    __syncthreads();
  }

  if (DO_FC) {
    float p = act ? hreg * wfc[q] : 0.f;
#pragma unroll
    for (int off = 32; off > 0; off >>= 1) p += __shfl_xor(p, off);
    if (lane == 0) out[me] = p + bfc[0];
  }
}

// -------- Layer 1: scalar input x[B][T] --------
__global__ __launch_bounds__(128, 2) void lstm_first(
    const float* __restrict__ x,     // [B][T]
    const float* __restrict__ wih,   // [4H][1]
    const float* __restrict__ whh,   // [4H][H]
    const float* __restrict__ bias,  // [4H]
    float* __restrict__ hseq)        // [T][B][H]
{
  __shared__ float s_h[2][Hp];
  __shared__ float s_ex[2][Hn][2];

  const int lane = threadIdx.x & 63;
  const int wv   = threadIdx.x >> 6;
  const int eb   = blockIdx.x * 2;
  const int me   = eb + wv;
  const bool act = lane < Hn;
  const int q    = act ? lane : 0;
  const int gA   = 2 * wv, gB = gA + 1;

  float whA[Hp], whB[Hp];
#pragma unroll
  for (int k = 0; k < Hn; ++k) {
    whA[k] = whh[(gA * Hn + q) * Hn + k];
    whB[k] = whh[(gB * Hn + q) * Hn + k];
  }
  whA[50] = whA[51] = whB[50] = whB[51] = 0.f;
  const float wiAs = wih[gA * Hn + q];
  const float wiBs = wih[gB * Hn + q];
  const float bA = act ? bias[gA * Hn + q] : 0.f;
  const float bB = act ? bias[gB * Hn + q] : 0.f;

  if (threadIdx.x < 2 * Hp) {
    s_h[threadIdx.x / Hp][threadIdx.x % Hp] = 0.f;
  }
  __syncthreads();

  float cst = 0.f, hreg = 0.f;

#pragma unroll 1
  for (int tb = 0; tb < Tn; tb += 64) {
    const float xv0 = x[(size_t)(eb + 0) * Tn + tb + lane];  // 64 steps staged
    const float xv1 = x[(size_t)(eb + 1) * Tn + tb + lane];
#pragma unroll 1
    for (int ti = 0; ti < 64; ++ti) {
      const float xk0 = rlane(xv0, ti);
      const float xk1 = rlane(xv1, ti);
      float aA0 = fmaf(wiAs, xk0, bA);
      float aB0 = fmaf(wiBs, xk0, bB);
      float aA1 = fmaf(wiAs, xk1, bA);
      float aB1 = fmaf(wiBs, xk1, bB);
#pragma unroll
      for (int kb = 0; kb < 13; ++kb) {
        const float4 vh0 = *(const float4*)&s_h[0][kb * 4];
        const float4 vh1 = *(const float4*)&s_h[1][kb * 4];
#define K4(dk, C)                                      \
  aA0 = fmaf(whA[kb * 4 + dk], vh0.C, aA0);            \
  aB0 = fmaf(whB[kb * 4 + dk], vh0.C, aB0);            \
  aA1 = fmaf(whA[kb * 4 + dk], vh1.C, aA1);            \
  aB1 = fmaf(whB[kb * 4 + dk], vh1.C, aB1);
        K4(0, x) K4(1, y) K4(2, z) K4(3, w)
#undef K4
      }

      const float exA = wv ? aA0 : aA1;
      const float exB = wv ? aB0 : aB1;
      const float myA = wv ? aA1 : aA0;
      const float myB = wv ? aB1 : aB0;
      if (act) {
        s_ex[1 - wv][q][0] = exA;
        s_ex[1 - wv][q][1] = exB;
      }
      __syncthreads();
      const float oA = s_ex[wv][q][0];
      const float oB = s_ex[wv][q][1];
      const float gi = wv ? oA : myA;
      const float gf = wv ? oB : myB;
      const float gg = wv ? myA : oA;
      const float go = wv ? myB : oB;
      const float I = fsig(gi), F = fsig(gf), G = ftanh(gg), O = fsig(go);
      cst  = fmaf(F, cst, I * G);
      hreg = O * ftanh(cst);

      if (act) {
        s_h[wv][lane] = hreg;
        hseq[((size_t)(tb + ti) * Bn + me) * Hn + lane] = hreg;
      }
      __syncthreads();
    }
  }
}

}  // namespace

extern "C" void kernel_launch(void* const* d_in, const int* in_sizes, int n_in,
                              void* d_out, int out_size, void* d_ws, size_t ws_size,
                              hipStream_t stream) {
  const float* x    = (const float*)d_in[0];
  const float* wih1 = (const float*)d_in[1];
  const float* whh1 = (const float*)d_in[2];
  const float* b1   = (const float*)d_in[3];
  const float* wih2 = (const float*)d_in[4];
  const float* whh2 = (const float*)d_in[5];
  const float* b2   = (const float*)d_in[6];
  const float* wih3 = (const float*)d_in[7];
  const float* whh3 = (const float*)d_in[8];
  const float* b3   = (const float*)d_in[9];
  const float* wfc  = (const float*)d_in[10];
  const float* bfc  = (const float*)d_in[11];
  float* out = (float*)d_out;

  float* buf = (float*)d_ws;  // [T][B][H] fp32 = 200 MiB (ws confirmed >= this in R1)

  dim3 grid(Bn / 2), blk(128);  // 1024 blocks x 2 waves; 2 elems/block
  lstm_first<<<grid, blk, 0, stream>>>(x, wih1, whh1, b1, buf);
  lstm_mid<true, false><<<grid, blk, 0, stream>>>(
      buf, wih2, whh2, b2, buf, nullptr, nullptr, nullptr);
  lstm_mid<false, true><<<grid, blk, 0, stream>>>(
      buf, wih3, whh3, b3, nullptr, wfc, bfc, out);
}